// Round 1
// baseline (2141.143 us; speedup 1.0000x reference)
//
#include <hip/hip_runtime.h>
#include <math.h>

#define NN 50000

__global__ void k_count(const int* __restrict__ dst, int E, float* __restrict__ deg) {
    int i = blockIdx.x * 256 + threadIdx.x;
    if (i < E) atomicAdd(&deg[dst[i]], 1.0f);
}

__global__ void k_dis(const float* __restrict__ deg, float* __restrict__ dis, int n) {
    int i = blockIdx.x * 256 + threadIdx.x;
    if (i < n) dis[i] = rsqrtf(deg[i] + 1.0f);
}

// y[v][o] = dis[v] * sum_k h[v][k] * W[k][o]
template<int IN, int OUT>
__global__ void k_xw(const float* __restrict__ h, const float* __restrict__ W,
                     const float* __restrict__ dis, float* __restrict__ y, int n) {
    __shared__ float sW[IN * OUT];
    for (int i = threadIdx.x; i < IN * OUT; i += blockDim.x) sW[i] = W[i];
    __syncthreads();
    int idx = blockIdx.x * blockDim.x + threadIdx.x;
    if (idx >= n * OUT) return;
    int v = idx / OUT, o = idx - v * OUT;
    const float* hr = h + (size_t)v * IN;
    float acc = 0.f;
#pragma unroll
    for (int k = 0; k < IN; ++k) acc += hr[k] * sW[k * OUT + o];
    y[idx] = dis[v] * acc;
}

// z[dst[e]][f] += y[src[e]][f]  (z pre-initialized to y for self-loops)
template<int F>
__global__ void k_scatter(const int* __restrict__ src, const int* __restrict__ dst, int E,
                          const float* __restrict__ y, float* __restrict__ z) {
    long long idx = (long long)blockIdx.x * blockDim.x + threadIdx.x;
    if (idx >= (long long)E * F) return;
    int e = (int)(idx / F);
    int f = (int)(idx - (long long)e * F);
    atomicAdd(&z[(size_t)dst[e] * F + f], y[(size_t)src[e] * F + f]);
}

// per-feature sum & sumsq of (dis[v] * z[v][f]) in double
template<int F>
__global__ void k_bn_stats(const float* __restrict__ z, const float* __restrict__ dis,
                           int n, double* __restrict__ stats) {
    const int RPI = 256 / F;  // rows handled per block-iteration
    int f = threadIdx.x % F;
    int rlane = threadIdx.x / F;
    double s = 0.0, ss = 0.0;
    for (int r = blockIdx.x * RPI + rlane; r < n; r += gridDim.x * RPI) {
        float v = dis[r] * z[(size_t)r * F + f];
        s += (double)v;
        ss += (double)v * (double)v;
    }
    __shared__ double sh[512];
    sh[threadIdx.x] = s;
    sh[256 + threadIdx.x] = ss;
    __syncthreads();
    if (threadIdx.x < F) {
        for (int j = threadIdx.x + F; j < 256; j += F) { s += sh[j]; ss += sh[256 + j]; }
        atomicAdd(&stats[f], s);
        atomicAdd(&stats[F + f], ss);
    }
}

// stats -> per-feature mult/add
template<int F>
__global__ void k_bn_fin(double* __restrict__ stats, const float* __restrict__ g,
                         const float* __restrict__ be, int n) {
    int f = threadIdx.x;
    if (f >= F) return;
    double mean = stats[f] / n;
    double var = stats[F + f] / n - mean * mean;
    if (var < 0.0) var = 0.0;
    double mult = (double)g[f] / sqrt(var + 1e-5);
    stats[2 * F + f] = mult;
    stats[3 * F + f] = (double)be[f] - mult * mean;
}

// hout = lrelu(mult[f] * (dis[v]*z[v][f]) + add[f])
template<int F>
__global__ void k_bn_apply(const float* __restrict__ z, const float* __restrict__ dis,
                           const double* __restrict__ stats, float* __restrict__ hout, int n) {
    int idx = blockIdx.x * 256 + threadIdx.x;
    if (idx >= n * F) return;
    int v = idx / F, f = idx - v * F;
    float val = dis[v] * z[idx];
    float t = (float)(stats[2 * F + f] * (double)val + stats[3 * F + f]);
    hout[idx] = t > 0.f ? t : 0.1f * t;
}

__global__ void k_final(const float* __restrict__ z, const float* __restrict__ dis,
                        const float* __restrict__ b4, float* __restrict__ out, int n) {
    int i = blockIdx.x * 256 + threadIdx.x;
    if (i < n) {
        float t = dis[i] * z[i] + b4[0];
        out[i] = 1.f / (1.f + expf(-t));
    }
}

extern "C" void kernel_launch(void* const* d_in, const int* in_sizes, int n_in,
                              void* d_out, int out_size, void* d_ws, size_t ws_size,
                              hipStream_t stream) {
    const float* x  = (const float*)d_in[0];
    const int*   ei = (const int*)d_in[1];
    const int E = in_sizes[1] / 2;
    const int* src = ei;
    const int* dst = ei + E;
    const float* W1 = (const float*)d_in[2];
    const float* g1 = (const float*)d_in[4];
    const float* be1= (const float*)d_in[5];
    const float* W2 = (const float*)d_in[6];
    const float* g2 = (const float*)d_in[8];
    const float* be2= (const float*)d_in[9];
    const float* W3 = (const float*)d_in[10];
    const float* g3 = (const float*)d_in[12];
    const float* be3= (const float*)d_in[13];
    const float* W4 = (const float*)d_in[14];
    const float* b4 = (const float*)d_in[15];
    float* out = (float*)d_out;

    // workspace layout
    float* deg = (float*)d_ws;                 // N
    float* dis = deg + NN;                     // N
    float* A   = dis + NN;                     // N*256
    float* B   = A + (size_t)NN * 256;         // N*256
    double* st = (double*)(B + (size_t)NN * 256); // 3 * 1024 doubles
    double* st0 = st, *st1 = st + 1024, *st2 = st + 2048;

    hipMemsetAsync(deg, 0, NN * sizeof(float), stream);
    hipMemsetAsync(st, 0, 3 * 1024 * sizeof(double), stream);

    k_count<<<(E + 255) / 256, 256, 0, stream>>>(dst, E, deg);
    k_dis<<<(NN + 255) / 256, 256, 0, stream>>>(deg, dis, NN);

    // ---- Layer 1: x(3) -> 64 ----
    k_xw<3, 64><<<(NN * 64 + 255) / 256, 256, 0, stream>>>(x, W1, dis, A, NN);
    hipMemcpyAsync(B, A, (size_t)NN * 64 * sizeof(float), hipMemcpyDeviceToDevice, stream);
    {
        long long tot = (long long)E * 64;
        k_scatter<64><<<(int)((tot + 255) / 256), 256, 0, stream>>>(src, dst, E, A, B);
    }
    k_bn_stats<64><<<512, 256, 0, stream>>>(B, dis, NN, st0);
    k_bn_fin<64><<<1, 64, 0, stream>>>(st0, g1, be1, NN);
    k_bn_apply<64><<<(NN * 64 + 255) / 256, 256, 0, stream>>>(B, dis, st0, A, NN);

    // ---- Layer 2: 64 -> 64 ----
    k_xw<64, 64><<<(NN * 64 + 255) / 256, 256, 0, stream>>>(A, W2, dis, B, NN);
    hipMemcpyAsync(A, B, (size_t)NN * 64 * sizeof(float), hipMemcpyDeviceToDevice, stream);
    {
        long long tot = (long long)E * 64;
        k_scatter<64><<<(int)((tot + 255) / 256), 256, 0, stream>>>(src, dst, E, B, A);
    }
    k_bn_stats<64><<<512, 256, 0, stream>>>(A, dis, NN, st1);
    k_bn_fin<64><<<1, 64, 0, stream>>>(st1, g2, be2, NN);
    k_bn_apply<64><<<(NN * 64 + 255) / 256, 256, 0, stream>>>(A, dis, st1, B, NN);

    // ---- Layer 3: 64 -> 256 ----
    k_xw<64, 256><<<(NN * 256 + 255) / 256, 256, 0, stream>>>(B, W3, dis, A, NN);
    hipMemcpyAsync(B, A, (size_t)NN * 256 * sizeof(float), hipMemcpyDeviceToDevice, stream);
    {
        long long tot = (long long)E * 256;
        k_scatter<256><<<(int)((tot + 255) / 256), 256, 0, stream>>>(src, dst, E, A, B);
    }
    k_bn_stats<256><<<512, 256, 0, stream>>>(B, dis, NN, st2);
    k_bn_fin<256><<<1, 256, 0, stream>>>(st2, g3, be3, NN);
    k_bn_apply<256><<<(NN * 256 + 255) / 256, 256, 0, stream>>>(B, dis, st2, A, NN);

    // ---- Layer 4: 256 -> 1, + sigmoid ----
    k_xw<256, 1><<<(NN + 255) / 256, 256, 0, stream>>>(A, W4, dis, B, NN);
    hipMemcpyAsync(deg, B, NN * sizeof(float), hipMemcpyDeviceToDevice, stream);
    k_scatter<1><<<(E + 255) / 256, 256, 0, stream>>>(src, dst, E, B, deg);
    k_final<<<(NN + 255) / 256, 256, 0, stream>>>(deg, dis, b4, out, NN);
}

// Round 2
// 696.926 us; speedup vs baseline: 3.0723x; 3.0723x over previous
//
#include <hip/hip_runtime.h>
#include <math.h>

#define NN 50000

// ---------------- CSR build ----------------
__global__ void k_counti(const int* __restrict__ dst, int E, int* __restrict__ cnt) {
    int i = blockIdx.x * 256 + threadIdx.x;
    if (i < E) atomicAdd(&cnt[dst[i]], 1);
}

__global__ void k_dis(const int* __restrict__ cnt, float* __restrict__ dis, int n) {
    int i = blockIdx.x * 256 + threadIdx.x;
    if (i < n) dis[i] = rsqrtf((float)cnt[i] + 1.0f);
}

__global__ void k_scan(const int* __restrict__ cnt, int* __restrict__ rowstart, int n, int E) {
    __shared__ int ssum[1024];
    int t = threadIdx.x;
    const int CH = (n + 1023) / 1024;
    int beg = t * CH, end = min(beg + CH, n);
    int s = 0;
    for (int i = beg; i < end; i++) s += cnt[i];
    ssum[t] = s; __syncthreads();
    int v = s;
    for (int off = 1; off < 1024; off <<= 1) {
        int o = (t >= off) ? ssum[t - off] : 0;
        __syncthreads();
        v += o; ssum[t] = v;
        __syncthreads();
    }
    int base = v - s;  // exclusive prefix
    for (int i = beg; i < end; i++) { rowstart[i] = base; base += cnt[i]; }
    if (t == 1023) rowstart[n] = E;
}

__global__ void k_fill(const int* __restrict__ src, const int* __restrict__ dst, int E,
                       const int* __restrict__ rowstart, int* __restrict__ cur,
                       int* __restrict__ adj) {
    int e = blockIdx.x * 256 + threadIdx.x;
    if (e < E) {
        int d = dst[e];
        int p = atomicAdd(&cur[d], 1);
        adj[rowstart[d] + p] = src[e];
    }
}

// ---------------- GEMMs ----------------
// simple per-(v,o) kernel for tiny IN (layer 1)
template<int IN, int OUT>
__global__ void k_xw_small(const float* __restrict__ h, const float* __restrict__ W,
                           const float* __restrict__ dis, float* __restrict__ y, int n) {
    __shared__ float sW[IN * OUT];
    for (int i = threadIdx.x; i < IN * OUT; i += blockDim.x) sW[i] = W[i];
    __syncthreads();
    int idx = blockIdx.x * blockDim.x + threadIdx.x;
    if (idx >= n * OUT) return;
    int v = idx / OUT, o = idx - v * OUT;
    const float* hr = h + (size_t)v * IN;
    float acc = 0.f;
#pragma unroll
    for (int k = 0; k < IN; ++k) acc += hr[k] * sW[k * OUT + o];
    y[idx] = dis[v] * acc;
}

// Register-tiled GEMM, IN=64 fixed. Block 256 threads computes TILE_R x OUT.
// C4 = float4-cols per thread, RPT = rows per thread, KP = K phases for W staging.
template<int OUT, int C4, int RPT, int KP>
__global__ __launch_bounds__(256, 2) void k_xw64(const float* __restrict__ h,
                                                 const float* __restrict__ W,
                                                 const float* __restrict__ dis,
                                                 float* __restrict__ y, int n) {
    constexpr int TX = OUT / (4 * C4);
    constexpr int TY = 256 / TX;
    constexpr int TILE_R = TY * RPT;
    constexpr int KCH = 64 / KP;       // k rows of W per phase
    __shared__ float sW[KCH * OUT];
    __shared__ float sH[TILE_R * 64];

    const int tid = threadIdx.x;
    const int row0 = blockIdx.x * TILE_R;
    // stage H tile (zero-pad tail rows)
    {
        const float4* H4 = (const float4*)(h + (size_t)row0 * 64);
        float4* sH4 = (float4*)sH;
        int lim = min(TILE_R, n - row0) * 16;
        for (int i = tid; i < TILE_R * 16; i += 256)
            sH4[i] = (i < lim) ? H4[i] : make_float4(0.f, 0.f, 0.f, 0.f);
    }
    const int tx = tid % TX;
    const int ty = tid / TX;
    float4 acc[RPT][C4];
#pragma unroll
    for (int r = 0; r < RPT; r++)
#pragma unroll
        for (int c = 0; c < C4; c++) acc[r][c] = make_float4(0.f, 0.f, 0.f, 0.f);

    const float4* sW4 = (const float4*)sW;
    const float4* sH4 = (const float4*)sH;

    for (int kp = 0; kp < KP; kp++) {
        if (kp) __syncthreads();
        {   // stage W phase
            const float4* W4 = (const float4*)W + (size_t)kp * KCH * (OUT / 4);
            float4* sWd = (float4*)sW;
            for (int i = tid; i < KCH * OUT / 4; i += 256) sWd[i] = W4[i];
        }
        __syncthreads();
#pragma unroll
        for (int k4 = 0; k4 < KCH / 4; k4++) {
            float4 hv[RPT];
#pragma unroll
            for (int r = 0; r < RPT; r++)
                hv[r] = sH4[(ty * RPT + r) * 16 + kp * (KCH / 4) + k4];
#pragma unroll
            for (int kk = 0; kk < 4; kk++) {
                float4 wv[C4];
#pragma unroll
                for (int c = 0; c < C4; c++)
                    wv[c] = sW4[(k4 * 4 + kk) * (OUT / 4) + tx * C4 + c];
#pragma unroll
                for (int r = 0; r < RPT; r++) {
                    float hs = kk == 0 ? hv[r].x : kk == 1 ? hv[r].y : kk == 2 ? hv[r].z : hv[r].w;
#pragma unroll
                    for (int c = 0; c < C4; c++) {
                        acc[r][c].x += hs * wv[c].x;
                        acc[r][c].y += hs * wv[c].y;
                        acc[r][c].z += hs * wv[c].z;
                        acc[r][c].w += hs * wv[c].w;
                    }
                }
            }
        }
    }
    // store
#pragma unroll
    for (int r = 0; r < RPT; r++) {
        int row = row0 + ty * RPT + r;
        if (row < n) {
            float dv = dis[row];
#pragma unroll
            for (int c = 0; c < C4; c++) {
                float4 o;
                o.x = acc[r][c].x * dv; o.y = acc[r][c].y * dv;
                o.z = acc[r][c].z * dv; o.w = acc[r][c].w * dv;
                ((float4*)y)[(size_t)row * (OUT / 4) + tx * C4 + c] = o;
            }
        }
    }
}

// layer 4: y[v] = dis[v] * dot(h[v][0:256], W4)  — one wave per row
__global__ void k_dot256(const float* __restrict__ h, const float* __restrict__ W4,
                         const float* __restrict__ dis, float* __restrict__ y, int n) {
    int row = blockIdx.x * 4 + (threadIdx.x >> 6);
    int lane = threadIdx.x & 63;
    if (row >= n) return;
    float4 hv = ((const float4*)h)[(size_t)row * 64 + lane];
    float4 wv = ((const float4*)W4)[lane];
    float s = hv.x * wv.x + hv.y * wv.y + hv.z * wv.z + hv.w * wv.w;
#pragma unroll
    for (int off = 32; off; off >>= 1) s += __shfl_down(s, off);
    if (lane == 0) y[row] = dis[row] * s;
}

// ---------------- CSR gather aggregation: z[d] = y[d] + sum_{s in adj[d]} y[s] ----------------
__global__ void k_gather64(const int* __restrict__ rowstart, const int* __restrict__ adj,
                           const float* __restrict__ y, float* __restrict__ z, int n) {
    int row = blockIdx.x * 4 + (threadIdx.x >> 6);
    int lane = threadIdx.x & 63;
    if (row >= n) return;
    int beg = rowstart[row], end = rowstart[row + 1];
    float acc = y[(size_t)row * 64 + lane];
    int j = beg;
    for (; j + 3 < end; j += 4) {
        int s0 = adj[j], s1 = adj[j + 1], s2 = adj[j + 2], s3 = adj[j + 3];
        float a0 = y[(size_t)s0 * 64 + lane];
        float a1 = y[(size_t)s1 * 64 + lane];
        float a2 = y[(size_t)s2 * 64 + lane];
        float a3 = y[(size_t)s3 * 64 + lane];
        acc += (a0 + a1) + (a2 + a3);
    }
    for (; j < end; j++) acc += y[(size_t)adj[j] * 64 + lane];
    z[(size_t)row * 64 + lane] = acc;
}

__global__ void k_gather256(const int* __restrict__ rowstart, const int* __restrict__ adj,
                            const float* __restrict__ y, float* __restrict__ z, int n) {
    int row = blockIdx.x * 4 + (threadIdx.x >> 6);
    int lane = threadIdx.x & 63;
    if (row >= n) return;
    const float4* y4 = (const float4*)y;
    int beg = rowstart[row], end = rowstart[row + 1];
    float4 acc = y4[(size_t)row * 64 + lane];
    int j = beg;
    for (; j + 3 < end; j += 4) {
        int s0 = adj[j], s1 = adj[j + 1], s2 = adj[j + 2], s3 = adj[j + 3];
        float4 a0 = y4[(size_t)s0 * 64 + lane];
        float4 a1 = y4[(size_t)s1 * 64 + lane];
        float4 a2 = y4[(size_t)s2 * 64 + lane];
        float4 a3 = y4[(size_t)s3 * 64 + lane];
        acc.x += (a0.x + a1.x) + (a2.x + a3.x);
        acc.y += (a0.y + a1.y) + (a2.y + a3.y);
        acc.z += (a0.z + a1.z) + (a2.z + a3.z);
        acc.w += (a0.w + a1.w) + (a2.w + a3.w);
    }
    for (; j < end; j++) {
        float4 a = y4[(size_t)adj[j] * 64 + lane];
        acc.x += a.x; acc.y += a.y; acc.z += a.z; acc.w += a.w;
    }
    z[(size_t)row * 256 + lane * 4 + 0] = acc.x;
    z[(size_t)row * 256 + lane * 4 + 1] = acc.y;
    z[(size_t)row * 256 + lane * 4 + 2] = acc.z;
    z[(size_t)row * 256 + lane * 4 + 3] = acc.w;
}

__global__ void k_gather1(const int* __restrict__ rowstart, const int* __restrict__ adj,
                          const float* __restrict__ y, float* __restrict__ z, int n) {
    int row = blockIdx.x * 256 + threadIdx.x;
    if (row >= n) return;
    int beg = rowstart[row], end = rowstart[row + 1];
    float acc = y[row];
    for (int j = beg; j < end; j++) acc += y[adj[j]];
    z[row] = acc;
}

// ---------------- BatchNorm ----------------
template<int F>
__global__ void k_bn_stats(const float* __restrict__ z, const float* __restrict__ dis,
                           int n, double* __restrict__ stats) {
    const int RPI = 256 / F;
    int f = threadIdx.x % F;
    int rlane = threadIdx.x / F;
    double s = 0.0, ss = 0.0;
    for (int r = blockIdx.x * RPI + rlane; r < n; r += gridDim.x * RPI) {
        float v = dis[r] * z[(size_t)r * F + f];
        s += (double)v;
        ss += (double)v * (double)v;
    }
    __shared__ double sh[512];
    sh[threadIdx.x] = s;
    sh[256 + threadIdx.x] = ss;
    __syncthreads();
    if (threadIdx.x < F) {
        for (int j = threadIdx.x + F; j < 256; j += F) { s += sh[j]; ss += sh[256 + j]; }
        atomicAdd(&stats[f], s);
        atomicAdd(&stats[F + f], ss);
    }
}

template<int F>
__global__ void k_bn_fin(double* __restrict__ stats, const float* __restrict__ g,
                         const float* __restrict__ be, int n) {
    int f = threadIdx.x;
    if (f >= F) return;
    double mean = stats[f] / n;
    double var = stats[F + f] / n - mean * mean;
    if (var < 0.0) var = 0.0;
    double mult = (double)g[f] / sqrt(var + 1e-5);
    stats[2 * F + f] = mult;
    stats[3 * F + f] = (double)be[f] - mult * mean;
}

template<int F>
__global__ void k_bn_apply(const float* __restrict__ z, const float* __restrict__ dis,
                           const double* __restrict__ stats, float* __restrict__ hout, int n) {
    int idx = blockIdx.x * 256 + threadIdx.x;
    if (idx >= n * F) return;
    int v = idx / F, f = idx - v * F;
    float val = dis[v] * z[idx];
    float t = (float)(stats[2 * F + f] * (double)val + stats[3 * F + f]);
    hout[idx] = t > 0.f ? t : 0.1f * t;
}

__global__ void k_final(const float* __restrict__ z, const float* __restrict__ dis,
                        const float* __restrict__ b4, float* __restrict__ out, int n) {
    int i = blockIdx.x * 256 + threadIdx.x;
    if (i < n) {
        float t = dis[i] * z[i] + b4[0];
        out[i] = 1.f / (1.f + expf(-t));
    }
}

extern "C" void kernel_launch(void* const* d_in, const int* in_sizes, int n_in,
                              void* d_out, int out_size, void* d_ws, size_t ws_size,
                              hipStream_t stream) {
    const float* x  = (const float*)d_in[0];
    const int*   ei = (const int*)d_in[1];
    const int E = in_sizes[1] / 2;
    const int* src = ei;
    const int* dst = ei + E;
    const float* W1 = (const float*)d_in[2];
    const float* g1 = (const float*)d_in[4];
    const float* be1= (const float*)d_in[5];
    const float* W2 = (const float*)d_in[6];
    const float* g2 = (const float*)d_in[8];
    const float* be2= (const float*)d_in[9];
    const float* W3 = (const float*)d_in[10];
    const float* g3 = (const float*)d_in[12];
    const float* be3= (const float*)d_in[13];
    const float* W4 = (const float*)d_in[14];
    const float* b4 = (const float*)d_in[15];
    float* out = (float*)d_out;

    // workspace layout (A,B first for 16B alignment)
    float*  A  = (float*)d_ws;                       // N*256
    float*  B  = A + (size_t)NN * 256;               // N*256
    double* st = (double*)(B + (size_t)NN * 256);    // 3*1024 doubles
    double *st0 = st, *st1 = st + 1024, *st2 = st + 2048;
    int* cnt      = (int*)(st + 3 * 1024);           // N (count, then cursor, then y4 scratch)
    int* rowstart = cnt + NN;                        // N+1 (+pad)
    int* adj      = rowstart + NN + 4;               // E
    float* dis    = (float*)(adj + E);               // N
    float* yv     = (float*)cnt;                     // reuse after CSR build

    hipMemsetAsync(cnt, 0, NN * sizeof(int), stream);
    hipMemsetAsync(st, 0, 3 * 1024 * sizeof(double), stream);

    // CSR by destination + dis
    k_counti<<<(E + 255) / 256, 256, 0, stream>>>(dst, E, cnt);
    k_dis<<<(NN + 255) / 256, 256, 0, stream>>>(cnt, dis, NN);
    k_scan<<<1, 1024, 0, stream>>>(cnt, rowstart, NN, E);
    hipMemsetAsync(cnt, 0, NN * sizeof(int), stream);
    k_fill<<<(E + 255) / 256, 256, 0, stream>>>(src, dst, E, rowstart, cnt, adj);

    const int gemm_grid = (NN + 63) / 64;   // 64 rows per block
    const int wave4_grid = (NN + 3) / 4;    // 4 rows per block (wave kernels)

    // ---- Layer 1: x(3) -> 64 ----
    k_xw_small<3, 64><<<(NN * 64 + 255) / 256, 256, 0, stream>>>(x, W1, dis, A, NN);
    k_gather64<<<wave4_grid, 256, 0, stream>>>(rowstart, adj, A, B, NN);
    k_bn_stats<64><<<512, 256, 0, stream>>>(B, dis, NN, st0);
    k_bn_fin<64><<<1, 64, 0, stream>>>(st0, g1, be1, NN);
    k_bn_apply<64><<<(NN * 64 + 255) / 256, 256, 0, stream>>>(B, dis, st0, A, NN);

    // ---- Layer 2: 64 -> 64 ----
    k_xw64<64, 1, 4, 1><<<gemm_grid, 256, 0, stream>>>(A, W2, dis, B, NN);
    k_gather64<<<wave4_grid, 256, 0, stream>>>(rowstart, adj, B, A, NN);
    k_bn_stats<64><<<512, 256, 0, stream>>>(A, dis, NN, st1);
    k_bn_fin<64><<<1, 64, 0, stream>>>(st1, g2, be2, NN);
    k_bn_apply<64><<<(NN * 64 + 255) / 256, 256, 0, stream>>>(A, dis, st1, B, NN);

    // ---- Layer 3: 64 -> 256 ----
    k_xw64<256, 2, 8, 2><<<gemm_grid, 256, 0, stream>>>(B, W3, dis, A, NN);
    k_gather256<<<wave4_grid, 256, 0, stream>>>(rowstart, adj, A, B, NN);
    k_bn_stats<256><<<512, 256, 0, stream>>>(B, dis, NN, st2);
    k_bn_fin<256><<<1, 256, 0, stream>>>(st2, g3, be3, NN);
    k_bn_apply<256><<<(NN * 256 + 255) / 256, 256, 0, stream>>>(B, dis, st2, A, NN);

    // ---- Layer 4: 256 -> 1, + sigmoid ----
    k_dot256<<<wave4_grid, 256, 0, stream>>>(A, W4, dis, yv, NN);
    k_gather1<<<(NN + 255) / 256, 256, 0, stream>>>(rowstart, adj, yv, B, NN);
    k_final<<<(NN + 255) / 256, 256, 0, stream>>>(B, dis, b4, out, NN);
}

// Round 3
// 579.476 us; speedup vs baseline: 3.6950x; 1.2027x over previous
//
#include <hip/hip_runtime.h>
#include <math.h>

#define NN 50000

// ---------------- CSR build ----------------
__global__ void k_counti(const int* __restrict__ dst, int E, int* __restrict__ cnt) {
    int i = blockIdx.x * 256 + threadIdx.x;
    if (i < E) atomicAdd(&cnt[dst[i]], 1);
}

__global__ void k_dis(const int* __restrict__ cnt, float* __restrict__ dis, int n) {
    int i = blockIdx.x * 256 + threadIdx.x;
    if (i < n) dis[i] = rsqrtf((float)cnt[i] + 1.0f);
}

__global__ void k_scan(const int* __restrict__ cnt, int* __restrict__ rowstart, int n, int E) {
    __shared__ int ssum[1024];
    int t = threadIdx.x;
    const int CH = (n + 1023) / 1024;
    int beg = t * CH, end = min(beg + CH, n);
    int s = 0;
    for (int i = beg; i < end; i++) s += cnt[i];
    ssum[t] = s; __syncthreads();
    int v = s;
    for (int off = 1; off < 1024; off <<= 1) {
        int o = (t >= off) ? ssum[t - off] : 0;
        __syncthreads();
        v += o; ssum[t] = v;
        __syncthreads();
    }
    int base = v - s;  // exclusive prefix
    for (int i = beg; i < end; i++) { rowstart[i] = base; base += cnt[i]; }
    if (t == 1023) rowstart[n] = E;
}

__global__ void k_fill(const int* __restrict__ src, const int* __restrict__ dst, int E,
                       const int* __restrict__ rowstart, int* __restrict__ cur,
                       int* __restrict__ adj) {
    int e = blockIdx.x * 256 + threadIdx.x;
    if (e < E) {
        int d = dst[e];
        int p = atomicAdd(&cur[d], 1);
        adj[rowstart[d] + p] = src[e];
    }
}

// ---------------- elementwise prescale: p = dis[v] * x ----------------
__global__ void k_pre3(const float* __restrict__ x, const float* __restrict__ dis,
                       float* __restrict__ p, int n3) {
    int i = blockIdx.x * 256 + threadIdx.x;
    if (i < n3) p[i] = dis[i / 3] * x[i];
}

// ---------------- gathers: z[d] = dis[d]*(p[d] + sum_{s in adj[d]} p[s]) ----------------
__global__ void k_gather3(const int* __restrict__ rowstart, const int* __restrict__ adj,
                          const float* __restrict__ p, const float* __restrict__ dis,
                          float* __restrict__ z, int n) {
    int row = blockIdx.x * 256 + threadIdx.x;
    if (row >= n) return;
    float a0 = p[row * 3], a1 = p[row * 3 + 1], a2 = p[row * 3 + 2];
    int beg = rowstart[row], end = rowstart[row + 1];
    for (int j = beg; j < end; j++) {
        int s = adj[j];
        a0 += p[s * 3]; a1 += p[s * 3 + 1]; a2 += p[s * 3 + 2];
    }
    float dv = dis[row];
    z[row * 3] = dv * a0; z[row * 3 + 1] = dv * a1; z[row * 3 + 2] = dv * a2;
}

__global__ void k_gather64(const int* __restrict__ rowstart, const int* __restrict__ adj,
                           const float* __restrict__ p, const float* __restrict__ dis,
                           float* __restrict__ z, int n) {
    int row = blockIdx.x * 4 + (threadIdx.x >> 6);
    int lane = threadIdx.x & 63;
    if (row >= n) return;
    int beg = rowstart[row], end = rowstart[row + 1];
    float acc = p[(size_t)row * 64 + lane];
    int j = beg;
    for (; j + 3 < end; j += 4) {
        int s0 = adj[j], s1 = adj[j + 1], s2 = adj[j + 2], s3 = adj[j + 3];
        float a0 = p[(size_t)s0 * 64 + lane];
        float a1 = p[(size_t)s1 * 64 + lane];
        float a2 = p[(size_t)s2 * 64 + lane];
        float a3 = p[(size_t)s3 * 64 + lane];
        acc += (a0 + a1) + (a2 + a3);
    }
    for (; j < end; j++) acc += p[(size_t)adj[j] * 64 + lane];
    z[(size_t)row * 64 + lane] = dis[row] * acc;
}

__global__ void k_gather1_final(const int* __restrict__ rowstart, const int* __restrict__ adj,
                                const float* __restrict__ q, const float* __restrict__ dis,
                                const float* __restrict__ b4, float* __restrict__ out, int n) {
    int row = blockIdx.x * 256 + threadIdx.x;
    if (row >= n) return;
    float acc = q[row];
    int beg = rowstart[row], end = rowstart[row + 1];
    for (int j = beg; j < end; j++) acc += q[adj[j]];
    float v = dis[row] * acc + b4[0];
    out[row] = 1.f / (1.f + expf(-v));
}

// ---------------- GEMM (IN=64) + fused BN column stats ----------------
// block: 256 threads <-> 64 rows. COLT threads across columns (float4), RG row groups.
template<int OUT, int KP>
__global__ __launch_bounds__(256) void k_gemm64_stats(const float* __restrict__ z,
        const float* __restrict__ W, float* __restrict__ t,
        double* __restrict__ st, int n) {
    constexpr int COLT = OUT / 4;
    constexpr int RG = 256 / COLT;
    constexpr int RPT = 64 / RG;
    constexpr int KCH = 64 / KP;
    __shared__ __align__(16) float sH[64 * 68];    // 17408 B (reused for stats reduce)
    __shared__ __align__(16) float sW[KCH * OUT];
    const int tid = threadIdx.x;
    const int r0 = blockIdx.x * 64;
    {   // stage H, padded stride 68 (kills row-bank aliasing), zero tail rows
        const float4* Z4 = (const float4*)z;
        for (int i = tid; i < 64 * 16; i += 256) {
            int r = i >> 4, c = i & 15;
            float4 v = (r0 + r < n) ? Z4[(size_t)(r0 + r) * 16 + c]
                                    : make_float4(0.f, 0.f, 0.f, 0.f);
            *(float4*)&sH[r * 68 + c * 4] = v;
        }
    }
    const int tx = tid % COLT;
    const int ty = tid / COLT;
    float4 acc[RPT];
#pragma unroll
    for (int r = 0; r < RPT; r++) acc[r] = make_float4(0.f, 0.f, 0.f, 0.f);
    const float4* sW4 = (const float4*)sW;

    for (int kp = 0; kp < KP; kp++) {
        if (kp) __syncthreads();
        {   // stage W phase (KCH x OUT)
            const float4* Wsrc = (const float4*)W + (size_t)kp * KCH * COLT;
            float4* sWd = (float4*)sW;
            for (int i = tid; i < KCH * COLT; i += 256) sWd[i] = Wsrc[i];
        }
        __syncthreads();
#pragma unroll
        for (int k4 = 0; k4 < KCH / 4; k4++) {
            float4 wv0 = sW4[(k4 * 4 + 0) * COLT + tx];
            float4 wv1 = sW4[(k4 * 4 + 1) * COLT + tx];
            float4 wv2 = sW4[(k4 * 4 + 2) * COLT + tx];
            float4 wv3 = sW4[(k4 * 4 + 3) * COLT + tx];
#pragma unroll
            for (int r = 0; r < RPT; r++) {
                int row = ty * RPT + r;
                float4 hv = *(const float4*)&sH[row * 68 + kp * KCH + k4 * 4];
                acc[r].x += hv.x * wv0.x + hv.y * wv1.x + hv.z * wv2.x + hv.w * wv3.x;
                acc[r].y += hv.x * wv0.y + hv.y * wv1.y + hv.z * wv2.y + hv.w * wv3.y;
                acc[r].z += hv.x * wv0.z + hv.y * wv1.z + hv.z * wv2.z + hv.w * wv3.z;
                acc[r].w += hv.x * wv0.w + hv.y * wv1.w + hv.z * wv2.w + hv.w * wv3.w;
            }
        }
    }
    // store outputs
    float4* T4 = (float4*)t;
#pragma unroll
    for (int r = 0; r < RPT; r++) {
        int row = r0 + ty * RPT + r;
        if (row < n) T4[(size_t)row * COLT + tx] = acc[r];
    }
    // fused BN stats (pad rows are zero -> contribute nothing)
    __syncthreads();
    double* redS = (double*)sH;
    double* redQ = redS + RG * OUT;
    double s0 = 0, s1 = 0, s2 = 0, s3 = 0, q0 = 0, q1 = 0, q2 = 0, q3 = 0;
#pragma unroll
    for (int r = 0; r < RPT; r++) {
        s0 += acc[r].x; q0 += (double)acc[r].x * acc[r].x;
        s1 += acc[r].y; q1 += (double)acc[r].y * acc[r].y;
        s2 += acc[r].z; q2 += (double)acc[r].z * acc[r].z;
        s3 += acc[r].w; q3 += (double)acc[r].w * acc[r].w;
    }
    int base = ty * OUT + tx * 4;
    redS[base + 0] = s0; redS[base + 1] = s1; redS[base + 2] = s2; redS[base + 3] = s3;
    redQ[base + 0] = q0; redQ[base + 1] = q1; redQ[base + 2] = q2; redQ[base + 3] = q3;
    __syncthreads();
    if (ty == 0) {
#pragma unroll
        for (int j = 0; j < 4; j++) {
            int c = tx * 4 + j;
            double S = 0, Q = 0;
            for (int g = 0; g < RG; g++) { S += redS[g * OUT + c]; Q += redQ[g * OUT + c]; }
            atomicAdd(&st[c], S);
            atomicAdd(&st[OUT + c], Q);
        }
    }
}

// GEMM IN=3 -> OUT=64 with fused stats
__global__ __launch_bounds__(256) void k_gemm3_stats(const float* __restrict__ z,
        const float* __restrict__ W, float* __restrict__ t,
        double* __restrict__ st, int n) {
    __shared__ float sH[64 * 4];
    __shared__ float sW[3 * 64];
    __shared__ double red[2 * 16 * 64];   // 16 KB
    const int tid = threadIdx.x;
    const int r0 = blockIdx.x * 64;
    for (int i = tid; i < 192; i += 256) {
        int r = i / 3, c = i - r * 3;
        sH[r * 4 + c] = (r0 + r < n) ? z[(size_t)(r0 + r) * 3 + c] : 0.f;
    }
    if (tid < 48) ((float4*)sW)[tid] = ((const float4*)W)[tid];
    __syncthreads();
    const int tx = tid & 15, ty = tid >> 4;
    float4 acc[4];
#pragma unroll
    for (int r = 0; r < 4; r++) acc[r] = make_float4(0.f, 0.f, 0.f, 0.f);
    const float4* sW4 = (const float4*)sW;
#pragma unroll
    for (int k = 0; k < 3; k++) {
        float4 wv = sW4[k * 16 + tx];
#pragma unroll
        for (int r = 0; r < 4; r++) {
            float hs = sH[(ty * 4 + r) * 4 + k];
            acc[r].x += hs * wv.x; acc[r].y += hs * wv.y;
            acc[r].z += hs * wv.z; acc[r].w += hs * wv.w;
        }
    }
    float4* T4 = (float4*)t;
#pragma unroll
    for (int r = 0; r < 4; r++) {
        int row = r0 + ty * 4 + r;
        if (row < n) T4[(size_t)row * 16 + tx] = acc[r];
    }
    double* redS = red;
    double* redQ = red + 16 * 64;
    double s0 = 0, s1 = 0, s2 = 0, s3 = 0, q0 = 0, q1 = 0, q2 = 0, q3 = 0;
#pragma unroll
    for (int r = 0; r < 4; r++) {
        s0 += acc[r].x; q0 += (double)acc[r].x * acc[r].x;
        s1 += acc[r].y; q1 += (double)acc[r].y * acc[r].y;
        s2 += acc[r].z; q2 += (double)acc[r].z * acc[r].z;
        s3 += acc[r].w; q3 += (double)acc[r].w * acc[r].w;
    }
    int base = ty * 64 + tx * 4;
    redS[base + 0] = s0; redS[base + 1] = s1; redS[base + 2] = s2; redS[base + 3] = s3;
    redQ[base + 0] = q0; redQ[base + 1] = q1; redQ[base + 2] = q2; redQ[base + 3] = q3;
    __syncthreads();
    if (ty == 0) {
#pragma unroll
        for (int j = 0; j < 4; j++) {
            int c = tx * 4 + j;
            double S = 0, Q = 0;
            for (int g = 0; g < 16; g++) { S += redS[g * 64 + c]; Q += redQ[g * 64 + c]; }
            atomicAdd(&st[c], S);
            atomicAdd(&st[64 + c], Q);
        }
    }
}

// stats -> mult/add
template<int F>
__global__ void k_bn_fin(double* __restrict__ stats, const float* __restrict__ g,
                         const float* __restrict__ be, int n) {
    int f = threadIdx.x;
    if (f >= F) return;
    double mean = stats[f] / n;
    double var = stats[F + f] / n - mean * mean;
    if (var < 0.0) var = 0.0;
    double mult = (double)g[f] / sqrt(var + 1e-5);
    stats[2 * F + f] = mult;
    stats[3 * F + f] = (double)be[f] - mult * mean;
}

// p = dis[v] * lrelu(mult*t + add)   (F=64)
__global__ void k_apply64(const float* __restrict__ t, const float* __restrict__ dis,
                          const double* __restrict__ st, float* __restrict__ p, int n) {
    int idx = blockIdx.x * 256 + threadIdx.x;   // float4 index
    if (idx >= n * 16) return;
    int row = idx >> 4, c = (idx & 15) * 4;
    float4 v = ((const float4*)t)[idx];
    float m0 = (float)st[128 + c], m1 = (float)st[129 + c],
          m2 = (float)st[130 + c], m3 = (float)st[131 + c];
    float a0 = (float)st[192 + c], a1 = (float)st[193 + c],
          a2 = (float)st[194 + c], a3 = (float)st[195 + c];
    float r0 = m0 * v.x + a0; r0 = r0 > 0.f ? r0 : 0.1f * r0;
    float r1 = m1 * v.y + a1; r1 = r1 > 0.f ? r1 : 0.1f * r1;
    float r2 = m2 * v.z + a2; r2 = r2 > 0.f ? r2 : 0.1f * r2;
    float r3 = m3 * v.w + a3; r3 = r3 > 0.f ? r3 : 0.1f * r3;
    float dv = dis[row];
    ((float4*)p)[idx] = make_float4(r0 * dv, r1 * dv, r2 * dv, r3 * dv);
}

// layer3 apply + layer4 dot fused: q[v] = dis[v] * dot(lrelu(bn(t3[v])), W4)
__global__ void k_apply3_dot(const float* __restrict__ t, const double* __restrict__ st,
                             const float* __restrict__ dis, const float* __restrict__ W4,
                             float* __restrict__ q, int n) {
    int row = blockIdx.x * 4 + (threadIdx.x >> 6);
    int lane = threadIdx.x & 63;
    if (row >= n) return;
    float4 v = ((const float4*)t)[(size_t)row * 64 + lane];
    int c = lane * 4;
    float m0 = (float)st[512 + c], m1 = (float)st[513 + c],
          m2 = (float)st[514 + c], m3 = (float)st[515 + c];
    float a0 = (float)st[768 + c], a1 = (float)st[769 + c],
          a2 = (float)st[770 + c], a3 = (float)st[771 + c];
    float b0 = m0 * v.x + a0; b0 = b0 > 0.f ? b0 : 0.1f * b0;
    float b1 = m1 * v.y + a1; b1 = b1 > 0.f ? b1 : 0.1f * b1;
    float b2 = m2 * v.z + a2; b2 = b2 > 0.f ? b2 : 0.1f * b2;
    float b3 = m3 * v.w + a3; b3 = b3 > 0.f ? b3 : 0.1f * b3;
    float4 w = ((const float4*)W4)[lane];
    float s = b0 * w.x + b1 * w.y + b2 * w.z + b3 * w.w;
#pragma unroll
    for (int off = 32; off; off >>= 1) s += __shfl_down(s, off);
    if (lane == 0) q[row] = dis[row] * s;
}

extern "C" void kernel_launch(void* const* d_in, const int* in_sizes, int n_in,
                              void* d_out, int out_size, void* d_ws, size_t ws_size,
                              hipStream_t stream) {
    const float* x  = (const float*)d_in[0];
    const int*   ei = (const int*)d_in[1];
    const int E = in_sizes[1] / 2;
    const int* src = ei;
    const int* dst = ei + E;
    const float* W1 = (const float*)d_in[2];
    const float* g1 = (const float*)d_in[4];
    const float* be1= (const float*)d_in[5];
    const float* W2 = (const float*)d_in[6];
    const float* g2 = (const float*)d_in[8];
    const float* be2= (const float*)d_in[9];
    const float* W3 = (const float*)d_in[10];
    const float* g3 = (const float*)d_in[12];
    const float* be3= (const float*)d_in[13];
    const float* W4 = (const float*)d_in[14];
    const float* b4 = (const float*)d_in[15];
    float* out = (float*)d_out;

    // workspace layout
    float* T = (float*)d_ws;                     // N*256 (GEMM outputs)
    float* P = T + (size_t)NN * 256;             // N*64  (prescaled features / p0)
    float* Z = P + (size_t)NN * 64;              // N*64  (aggregated)
    float* Q = Z + (size_t)NN * 64;              // N     (layer4 dots)
    double* st = (double*)(Q + NN);              // 3*1024 doubles
    double *st0 = st, *st1 = st + 1024, *st2 = st + 2048;
    int* cnt      = (int*)(st + 3 * 1024);       // N
    int* rowstart = cnt + NN;                    // N+1 (+pad)
    int* adj      = rowstart + NN + 8;           // E
    float* dis    = (float*)(adj + E);           // N

    hipMemsetAsync(cnt, 0, NN * sizeof(int), stream);
    hipMemsetAsync(st, 0, 3 * 1024 * sizeof(double), stream);

    // CSR by destination + dis
    k_counti<<<(E + 255) / 256, 256, 0, stream>>>(dst, E, cnt);
    k_dis<<<(NN + 255) / 256, 256, 0, stream>>>(cnt, dis, NN);
    k_scan<<<1, 1024, 0, stream>>>(cnt, rowstart, NN, E);
    hipMemsetAsync(cnt, 0, NN * sizeof(int), stream);
    k_fill<<<(E + 255) / 256, 256, 0, stream>>>(src, dst, E, rowstart, cnt, adj);

    const int rows_grid = (NN + 255) / 256;      // 196
    const int wave4_grid = (NN + 3) / 4;         // 12500
    const int gemm_grid = (NN + 63) / 64;        // 782
    const int app_grid = (NN * 16 + 255) / 256;  // 3125

    // ---- Layer 1: aggregate at width 3, then GEMM 3->64 ----
    k_pre3<<<(NN * 3 + 255) / 256, 256, 0, stream>>>(x, dis, P, NN * 3);
    k_gather3<<<rows_grid, 256, 0, stream>>>(rowstart, adj, P, dis, Z, NN);
    k_gemm3_stats<<<gemm_grid, 256, 0, stream>>>(Z, W1, T, st0, NN);
    k_bn_fin<64><<<1, 64, 0, stream>>>(st0, g1, be1, NN);
    k_apply64<<<app_grid, 256, 0, stream>>>(T, dis, st0, P, NN);

    // ---- Layer 2: gather64, GEMM 64->64 ----
    k_gather64<<<wave4_grid, 256, 0, stream>>>(rowstart, adj, P, dis, Z, NN);
    k_gemm64_stats<64, 1><<<gemm_grid, 256, 0, stream>>>(Z, W2, T, st1, NN);
    k_bn_fin<64><<<1, 64, 0, stream>>>(st1, g2, be2, NN);
    k_apply64<<<app_grid, 256, 0, stream>>>(T, dis, st1, P, NN);

    // ---- Layer 3: gather64, GEMM 64->256 ----
    k_gather64<<<wave4_grid, 256, 0, stream>>>(rowstart, adj, P, dis, Z, NN);
    k_gemm64_stats<256, 2><<<gemm_grid, 256, 0, stream>>>(Z, W3, T, st2, NN);
    k_bn_fin<256><<<1, 256, 0, stream>>>(st2, g3, be3, NN);

    // ---- Layer 3 apply + Layer 4 dot fused, then scalar gather + sigmoid ----
    k_apply3_dot<<<wave4_grid, 256, 0, stream>>>(T, st2, dis, W4, Q, NN);
    k_gather1_final<<<rows_grid, 256, 0, stream>>>(rowstart, adj, Q, dis, b4, out, NN);
}